// Round 9
// baseline (1965.694 us; speedup 1.0000x reference)
//
#include <hip/hip_runtime.h>
#include <math.h>

#define T_STEPS 100
#define BATCH   1024
#define INDIM   40
#define HID     512
#define NBLK    4
#define KPAD    576          // 64 (padded x) + 512 (h)
#define NG      2048         // 4*HID gate width

typedef int v4i __attribute__((ext_vector_type(4)));

// Bit-faithful emulation of the reference f32 _pact: sign(x)*0.5*((|x| - ||x|-a|) + a)
__device__ __forceinline__ float pact_f(float x, float a){
    float u = fabsf(x);
    float v = fabsf(u - a);
    float s = (x > 0.f) ? 1.f : ((x < 0.f) ? -1.f : 0.f);
    return (s * 0.5f) * ((u - v) + a);
}
__device__ __forceinline__ int quant_int(float x, float inv_a){
    float xs = x * inv_a;
    xs = fminf(fmaxf(xs, -127.f/128.f), 127.f/128.f);
    return (int)rintf(xs * 128.f);
}
__device__ __forceinline__ int clamp127(int v){
    return v > 127 ? 127 : (v < -127 ? -127 : v);
}

// ---------------- setup kernels ----------------
__global__ __launch_bounds__(256) void k_quant_x(const float* __restrict__ x,
                                                 signed char* __restrict__ xq){
    int idx = blockIdx.x * 256 + threadIdx.x;     // over T*B*64
    int k = idx & 63; int tb = idx >> 6;
    signed char q = 0;
    if (k < INDIM){
        float xv = x[tb * INDIM + k];
        float pv = pact_f(xv, 128.f);
        q = (signed char)quant_int(pv, 1.f/128.f);
    }
    xq[idx] = q;
}

// W stored as Wt[n][c_new][k]; c_new = (h>>4)*64 + gate*16 + (h&15)  <->  o = gate*512 + h
__global__ __launch_bounds__(256) void k_quant_w(const float* __restrict__ wih,
                                                 const float* __restrict__ whh,
                                                 signed char* __restrict__ wt){
    int idx = blockIdx.x * 256 + threadIdx.x;     // over NBLK*NG*KPAD
    int kk = idx % KPAD;
    int no = idx / KPAD;
    int c  = no % NG;
    int n  = no / NG;
    int gate = (c >> 4) & 3;
    int h    = ((c >> 6) << 4) | (c & 15);
    int o    = gate * 512 + h;
    float w;
    if (kk < INDIM)      w = wih[((long)n*INDIM + kk)*NG + o];
    else if (kk < 64)    { wt[idx] = 0; return; }
    else                 w = whh[((long)n*HID + (kk-64))*NG + o];
    w = fminf(fmaxf(w, -1.f), 1.f);
    wt[idx] = (signed char)quant_int(w, 1.f);
}

__global__ __launch_bounds__(256) void k_quant_bias(const float* __restrict__ bih,
                                                    const float* __restrict__ bhh,
                                                    int* __restrict__ bihq,
                                                    int* __restrict__ bhhq){
    int idx = blockIdx.x * 256 + threadIdx.x;     // NBLK*NG, permuted order
    int c = idx % NG; int n = idx / NG;
    int gate = (c >> 4) & 3;
    int h    = ((c >> 6) << 4) | (c & 15);
    int o    = gate * 512 + h;
    bihq[idx] = quant_int(bih[n*NG + o], 1.f);
    bhhq[idx] = quant_int(bhh[n*NG + o], 1.f);
}

__global__ __launch_bounds__(256) void k_quant_fc(const float* __restrict__ fcw,
                                                  const float* __restrict__ fcb,
                                                  signed char* __restrict__ fcwt,
                                                  int* __restrict__ fcbq){
    int idx = blockIdx.x * 256 + threadIdx.x;     // NBLK*3*512
    if (idx < NBLK*3*512){
        int k = idx % 512; int nc = idx / 512; int c = nc % 3; int n = nc / 3;
        float w = fcw[((long)n*HID + k)*3 + c];
        w = fminf(fmaxf(w, -1.f), 1.f);
        fcwt[idx] = (signed char)quant_int(w, 1.f);
    }
    if (idx < NBLK*3) fcbq[idx] = quant_int(fcb[idx], 1.f);
}

__global__ void k_luts(signed char* __restrict__ sigl, signed char* __restrict__ thl){
    int i = threadIdx.x;
    if (i < 255){
        double xv = (double)(i - 127) / 32.0;
        float s = (float)(1.0 / (1.0 + exp(-xv)));
        float t = (float)tanh(xv);
        sigl[i] = (signed char)quant_int(pact_f(s, 1.f), 1.f);
        thl[i]  = (signed char)quant_int(pact_f(t, 1.f), 1.f);
    }
}

// ---------------- fused per-step kernel: gates GEMM + cell update ----------------
// 512 blocks (2/CU), 4 waves (2m x 2n), block tile 128x128, wave tile 64x64.
// NO LDS staging: A and B MFMA fragments are read DIRECTLY from global memory
// (rows 64B-aligned; a wave's 64 lanes cover 16 rows x 64B = perfect 64B
// segments). 2-deep register double-buffer over the 9 K-slabs; zero barriers
// in the K-loop. LDS holds only the 255-entry LUTs. Biases folded into
// accumulator init (bit-exact). XCD-affine: bid&7 = XCD (W+H L2-resident).
__global__ __launch_bounds__(256, 2) void k_step(const signed char* __restrict__ xq_t,
                                                 const signed char* __restrict__ Hin,
                                                 signed char* __restrict__ Hout,
                                                 signed char* __restrict__ C,
                                                 const signed char* __restrict__ Wt,
                                                 const int* __restrict__ bihq,
                                                 const int* __restrict__ bhhq,
                                                 const signed char* __restrict__ sigl,
                                                 const signed char* __restrict__ thl){
    __shared__ signed char s_sig[256], s_th[256];

    int bid = blockIdx.x;
    int xcd = bid & 7, slot = bid >> 3;            // slot in [0,64)
    int n   = xcd >> 1;
    int idx = ((xcd & 1) << 6) | slot;             // [0,128)
    int bm  = idx & 7;                             // 8 x 128-row blocks
    int bn  = idx >> 3;                            // 16 x 128-col blocks

    int tid  = threadIdx.x;
    int lane = tid & 63;
    int wave = tid >> 6;
    int wm = wave >> 1, wn = wave & 1;

    if (tid < 255){ s_sig[tid] = sigl[tid]; s_th[tid] = thl[tid]; }
    __syncthreads();                               // LUTs ready; only barrier

    // per-lane coordinates
    int am  = wm*64 + (lane & 15);                 // A row within 128-row tile
    int bo  = wn*64 + (lane & 15);                 // B col-row within 128-col tile
    int ak  = (lane >> 4) * 16;                    // 16B k-chunk
    int hglob = bn*32 + wn*16 + (lane & 15);
    int rbase = bm*128 + wm*64 + ((lane >> 4) << 2);
    int cbase = bn*128 + wn*64 + (lane & 15);

    // C preload ([n][h][b], word-packed rows) — latency hides under GEMM
    int* Cw = (int*)(C + ((long)(n*HID + hglob))*BATCH + rbase);
    int cold[4];
    #pragma unroll
    for (int mi = 0; mi < 4; ++mi) cold[mi] = Cw[mi*4];

    // fragment base pointers (loop-invariant; slab offsets are immediates)
    const signed char* pA[4];
    const signed char* pW[4];
    #pragma unroll
    for (int mi = 0; mi < 4; ++mi)
        pA[mi] = Hin + ((long)(n*BATCH + bm*128 + am + mi*16))*HID + ak;
    #pragma unroll
    for (int ni = 0; ni < 4; ++ni)
        pW[ni] = Wt + ((long)(n*NG + bn*128 + bo + ni*16))*KPAD + ak;

    // 2-deep register double-buffer
    v4i afb[2][4], bfb[2][4];
    #pragma unroll
    for (int mi = 0; mi < 4; ++mi)
        afb[0][mi] = *(const v4i*)(xq_t + (bm*128 + am + mi*16)*64 + ak);  // slab 0 = X
    #pragma unroll
    for (int ni = 0; ni < 4; ++ni) bfb[0][ni] = *(const v4i*)(pW[ni]);
    #pragma unroll
    for (int mi = 0; mi < 4; ++mi) afb[1][mi] = *(const v4i*)(pA[mi]);     // slab 1
    #pragma unroll
    for (int ni = 0; ni < 4; ++ni) bfb[1][ni] = *(const v4i*)(pW[ni] + 64);

    int q12p[4][4];
    {   // ---- kt = 0: x part (acc1 scoped; bias b1 folded into init) ----
        v4i acc1[4][4];
        #pragma unroll
        for (int ni = 0; ni < 4; ++ni){
            int b1 = bihq[n*NG + cbase + ni*16];
            #pragma unroll
            for (int mi = 0; mi < 4; ++mi) acc1[mi][ni] = (v4i){b1, b1, b1, b1};
        }
        #pragma unroll
        for (int mi = 0; mi < 4; ++mi)
            #pragma unroll
            for (int ni = 0; ni < 4; ++ni)
                acc1[mi][ni] = __builtin_amdgcn_mfma_i32_16x16x64_i8(afb[0][mi], bfb[0][ni], acc1[mi][ni], 0, 0, 0);
        // refill buf0 with slab 2 (fire while packing)
        #pragma unroll
        for (int mi = 0; mi < 4; ++mi) afb[0][mi] = *(const v4i*)(pA[mi] + 64);
        #pragma unroll
        for (int ni = 0; ni < 4; ++ni) bfb[0][ni] = *(const v4i*)(pW[ni] + 128);
        // pack q12 (frees acc1)
        #pragma unroll
        for (int mi = 0; mi < 4; ++mi)
            #pragma unroll
            for (int ni = 0; ni < 4; ++ni){
                int pk = 0;
                #pragma unroll
                for (int r = 0; r < 4; ++r){
                    int q = clamp127((int)rintf((float)acc1[mi][ni][r] * 0.25f));
                    pk |= (q & 255) << (8*r);
                }
                q12p[mi][ni] = pk;
            }
    }

    // ---- kt = 1..8: h part (acc2; bias 32*b2 folded into init) ----
    v4i acc2[4][4];
    #pragma unroll
    for (int ni = 0; ni < 4; ++ni){
        int b2 = 32 * bhhq[n*NG + cbase + ni*16];
        #pragma unroll
        for (int mi = 0; mi < 4; ++mi) acc2[mi][ni] = (v4i){b2, b2, b2, b2};
    }
    #pragma unroll
    for (int kt = 1; kt < 9; ++kt){
        int cb = kt & 1;
        #pragma unroll
        for (int mi = 0; mi < 4; ++mi)
            #pragma unroll
            for (int ni = 0; ni < 4; ++ni)
                acc2[mi][ni] = __builtin_amdgcn_mfma_i32_16x16x64_i8(afb[cb][mi], bfb[cb][ni], acc2[mi][ni], 0, 0, 0);
        if (kt + 2 <= 8){   // refill this buffer with slab kt+2
            #pragma unroll
            for (int mi = 0; mi < 4; ++mi) afb[cb][mi] = *(const v4i*)(pA[mi] + (kt+1)*64);
            #pragma unroll
            for (int ni = 0; ni < 4; ++ni) bfb[cb][ni] = *(const v4i*)(pW[ni] + (kt+2)*64);
        }
    }

    // fused epilogue: gates -> cell update; H bytes out, C word RMW (R4 math)
    #pragma unroll
    for (int mi = 0; mi < 4; ++mi){
        int cw = cold[mi];
        int cnew = 0;
        #pragma unroll
        for (int r = 0; r < 4; ++r){
            int g4[4];
            #pragma unroll
            for (int ni = 0; ni < 4; ++ni){
                int q13 = clamp127((int)rintf((float)acc2[mi][ni][r] * 0.0078125f));
                int q12 = (signed char)(q12p[mi][ni] >> (8*r));
                g4[ni]  = clamp127(q12 + q13);
            }
            int ig = s_sig[g4[0] + 127];
            int jg = s_th [g4[1] + 127];
            int fg = s_sig[g4[2] + 127];
            int og = s_sig[g4[3] + 127];
            int cc = (signed char)(cw >> (8*r));
            int gc = clamp127((int)rintf((float)(cc * fg) * 0.0078125f));   // /128
            int ai = clamp127((int)rintf((float)(ig * jg) * 0.0078125f));   // /128
            int nc = clamp127((int)rintf((float)(4*gc + ai) * 0.25f));      // /4
            int ac = s_th[nc + 127];
            int nh = clamp127((int)rintf((float)(ac * og) * (1.0f/512.0f)));// /512
            cnew |= (nc & 255) << (8*r);
            Hout[((long)(n*BATCH) + rbase + mi*16 + r)*HID + hglob] = (signed char)nh;
        }
        Cw[mi*4] = cnew;
    }
}

// ---------------- final fc ----------------
__global__ __launch_bounds__(256) void k_fc(const signed char* __restrict__ H,
                                            const signed char* __restrict__ fcwt,
                                            const int* __restrict__ fcbq,
                                            float* __restrict__ out){
    int wave = threadIdx.x >> 6, lane = threadIdx.x & 63;
    int nb = blockIdx.x * 4 + wave;                // n*1024+b
    int n = nb >> 10, b = nb & 1023;
    const signed char* h = H + (long)nb * HID + lane * 8;
    int2 hv = *(const int2*)h;
    int acc[3] = {0, 0, 0};
    #pragma unroll
    for (int c = 0; c < 3; ++c){
        const signed char* wp = fcwt + ((long)(n*3 + c))*512 + lane*8;
        int2 wv = *(const int2*)wp;
        int s = 0;
        #pragma unroll
        for (int e = 0; e < 4; ++e){
            s += (int)(signed char)(hv.x >> (8*e)) * (int)(signed char)(wv.x >> (8*e));
            s += (int)(signed char)(hv.y >> (8*e)) * (int)(signed char)(wv.y >> (8*e));
        }
        acc[c] = s;
    }
    #pragma unroll
    for (int off = 32; off; off >>= 1){
        acc[0] += __shfl_down(acc[0], off, 64);
        acc[1] += __shfl_down(acc[1], off, 64);
        acc[2] += __shfl_down(acc[2], off, 64);
    }
    if (lane == 0){
        #pragma unroll
        for (int c = 0; c < 3; ++c){
            int v = acc[c] + 32 * fcbq[n*3 + c];
            int q = clamp127((int)rintf((float)v * (1.0f/512.0f)));
            out[b*12 + n*3 + c] = (float)q * 0.125f;
        }
    }
}

extern "C" void kernel_launch(void* const* d_in, const int* in_sizes, int n_in,
                              void* d_out, int out_size, void* d_ws, size_t ws_size,
                              hipStream_t stream)
{
    const float* x   = (const float*)d_in[0];
    const float* wih = (const float*)d_in[1];
    const float* whh = (const float*)d_in[2];
    const float* bih = (const float*)d_in[3];
    const float* bhh = (const float*)d_in[4];
    const float* fcw = (const float*)d_in[6];
    const float* fcb = (const float*)d_in[7];
    float* out = (float*)d_out;
    (void)in_sizes; (void)n_in; (void)out_size; (void)ws_size;

    char* p = (char*)d_ws;
    auto alloc = [&](size_t nbytes){ char* r = p; p += (nbytes + 255) & ~(size_t)255; return r; };
    signed char* Xq   = (signed char*)alloc((size_t)T_STEPS*BATCH*64);
    signed char* Wt   = (signed char*)alloc((size_t)NBLK*NG*KPAD);
    signed char* Hb0  = (signed char*)alloc((size_t)NBLK*BATCH*HID);
    signed char* Hb1  = (signed char*)alloc((size_t)NBLK*BATCH*HID);
    signed char* Cb   = (signed char*)alloc((size_t)NBLK*BATCH*HID);
    int*         bihq = (int*)alloc((size_t)NBLK*NG*4);
    int*         bhhq = (int*)alloc((size_t)NBLK*NG*4);
    signed char* fcwt = (signed char*)alloc((size_t)NBLK*3*512);
    int*         fcbq = (int*)alloc((size_t)NBLK*3*4);
    signed char* sigl = (signed char*)alloc(256);
    signed char* thl  = (signed char*)alloc(256);

    k_quant_x   <<<(T_STEPS*BATCH*64)/256, 256, 0, stream>>>(x, Xq);
    k_quant_w   <<<(NBLK*NG*KPAD)/256,     256, 0, stream>>>(wih, whh, Wt);
    k_quant_bias<<<(NBLK*NG)/256,          256, 0, stream>>>(bih, bhh, bihq, bhhq);
    k_quant_fc  <<<(NBLK*3*512)/256,       256, 0, stream>>>(fcw, fcb, fcwt, fcbq);
    k_luts      <<<1, 256, 0, stream>>>(sigl, thl);
    hipMemsetAsync(Hb0, 0, (size_t)3*NBLK*BATCH*HID, stream);   // Hb0+Hb1+Cb contiguous

    for (int t = 0; t < T_STEPS; ++t){
        const signed char* Hi = (t & 1) ? Hb1 : Hb0;
        signed char*       Ho = (t & 1) ? Hb0 : Hb1;
        k_step<<<512, 256, 0, stream>>>(Xq + (size_t)t*BATCH*64, Hi, Ho, Cb, Wt, bihq, bhhq, sigl, thl);
    }
    k_fc<<<(NBLK*BATCH)/4, 256, 0, stream>>>(Hb0, fcwt, fcbq, out);   // t=99 wrote Hb0
}

// Round 10
// 1836.423 us; speedup vs baseline: 1.0704x; 1.0704x over previous
//
#include <hip/hip_runtime.h>
#include <math.h>

#define T_STEPS 100
#define BATCH   1024
#define INDIM   40
#define HID     512
#define NBLK    4
#define KPAD    576          // 64 (padded x) + 512 (h)
#define NG      2048         // 4*HID gate width
#define LDAP    80           // padded LDS row stride (bytes) for 64B k-slab

typedef int v4i __attribute__((ext_vector_type(4)));

// Bit-faithful emulation of the reference f32 _pact: sign(x)*0.5*((|x| - ||x|-a|) + a)
__device__ __forceinline__ float pact_f(float x, float a){
    float u = fabsf(x);
    float v = fabsf(u - a);
    float s = (x > 0.f) ? 1.f : ((x < 0.f) ? -1.f : 0.f);
    return (s * 0.5f) * ((u - v) + a);
}
__device__ __forceinline__ int quant_int(float x, float inv_a){
    float xs = x * inv_a;
    xs = fminf(fmaxf(xs, -127.f/128.f), 127.f/128.f);
    return (int)rintf(xs * 128.f);
}
__device__ __forceinline__ int clamp127(int v){
    return v > 127 ? 127 : (v < -127 ? -127 : v);
}

// ---------------- setup kernels ----------------
__global__ __launch_bounds__(256) void k_quant_x(const float* __restrict__ x,
                                                 signed char* __restrict__ xq){
    int idx = blockIdx.x * 256 + threadIdx.x;     // over T*B*64
    int k = idx & 63; int tb = idx >> 6;
    signed char q = 0;
    if (k < INDIM){
        float xv = x[tb * INDIM + k];
        float pv = pact_f(xv, 128.f);
        q = (signed char)quant_int(pv, 1.f/128.f);
    }
    xq[idx] = q;
}

// W stored as Wt[n][c_new][k]; c_new = (h>>4)*64 + gate*16 + (h&15)  <->  o = gate*512 + h
__global__ __launch_bounds__(256) void k_quant_w(const float* __restrict__ wih,
                                                 const float* __restrict__ whh,
                                                 signed char* __restrict__ wt){
    int idx = blockIdx.x * 256 + threadIdx.x;     // over NBLK*NG*KPAD
    int kk = idx % KPAD;
    int no = idx / KPAD;
    int c  = no % NG;
    int n  = no / NG;
    int gate = (c >> 4) & 3;
    int h    = ((c >> 6) << 4) | (c & 15);
    int o    = gate * 512 + h;
    float w;
    if (kk < INDIM)      w = wih[((long)n*INDIM + kk)*NG + o];
    else if (kk < 64)    { wt[idx] = 0; return; }
    else                 w = whh[((long)n*HID + (kk-64))*NG + o];
    w = fminf(fmaxf(w, -1.f), 1.f);
    wt[idx] = (signed char)quant_int(w, 1.f);
}

__global__ __launch_bounds__(256) void k_quant_bias(const float* __restrict__ bih,
                                                    const float* __restrict__ bhh,
                                                    int* __restrict__ bihq,
                                                    int* __restrict__ bhhq){
    int idx = blockIdx.x * 256 + threadIdx.x;     // NBLK*NG, permuted order
    int c = idx % NG; int n = idx / NG;
    int gate = (c >> 4) & 3;
    int h    = ((c >> 6) << 4) | (c & 15);
    int o    = gate * 512 + h;
    bihq[idx] = quant_int(bih[n*NG + o], 1.f);
    bhhq[idx] = quant_int(bhh[n*NG + o], 1.f);
}

__global__ __launch_bounds__(256) void k_quant_fc(const float* __restrict__ fcw,
                                                  const float* __restrict__ fcb,
                                                  signed char* __restrict__ fcwt,
                                                  int* __restrict__ fcbq){
    int idx = blockIdx.x * 256 + threadIdx.x;     // NBLK*3*512
    if (idx < NBLK*3*512){
        int k = idx % 512; int nc = idx / 512; int c = nc % 3; int n = nc / 3;
        float w = fcw[((long)n*HID + k)*3 + c];
        w = fminf(fmaxf(w, -1.f), 1.f);
        fcwt[idx] = (signed char)quant_int(w, 1.f);
    }
    if (idx < NBLK*3) fcbq[idx] = quant_int(fcb[idx], 1.f);
}

__global__ void k_luts(signed char* __restrict__ sigl, signed char* __restrict__ thl){
    int i = threadIdx.x;
    if (i < 255){
        double xv = (double)(i - 127) / 32.0;
        float s = (float)(1.0 / (1.0 + exp(-xv)));
        float t = (float)tanh(xv);
        sigl[i] = (signed char)quant_int(pact_f(s, 1.f), 1.f);
        thl[i]  = (signed char)quant_int(pact_f(t, 1.f), 1.f);
    }
}

// ---------------- fused per-step kernel: gates GEMM + cell update ----------------
// 512 blocks (2/CU), 4 waves (2m x 2n), block tile 128x128, wave tile 64x64.
// R4 structure; ONE change: A (X/H) fragments read DIRECT from global into a
// 2-deep register double-buffer (prefetched one phase ahead, covered by the
// barrier rhythm). Only W goes through LDS (halves LDS instr count).
// XCD-affine: bid&7 = XCD; two XCDs serve one n (W+H L2-resident).
__global__ __launch_bounds__(256, 2) void k_step(const signed char* __restrict__ xq_t,
                                                 const signed char* __restrict__ Hin,
                                                 signed char* __restrict__ Hout,
                                                 signed char* __restrict__ C,
                                                 const signed char* __restrict__ Wt,
                                                 const int* __restrict__ bihq,
                                                 const int* __restrict__ bhhq,
                                                 const signed char* __restrict__ sigl,
                                                 const signed char* __restrict__ thl){
    __shared__ __align__(16) signed char Ws[2][128*LDAP];
    __shared__ signed char s_sig[256], s_th[256];

    int bid = blockIdx.x;
    int xcd = bid & 7, slot = bid >> 3;            // slot in [0,64)
    int n   = xcd >> 1;
    int idx = ((xcd & 1) << 6) | slot;             // [0,128)
    int bm  = idx & 7;                             // 8 x 128-row blocks
    int bn  = idx >> 3;                            // 16 x 128-col blocks

    int tid  = threadIdx.x;
    int lane = tid & 63;
    int wave = tid >> 6;
    int wm = wave >> 1, wn = wave & 1;

    if (tid < 255){ s_sig[tid] = sigl[tid]; s_th[tid] = thl[tid]; }

    // per-lane output coordinates
    int hglob = bn*32 + wn*16 + (lane & 15);
    int rbase = bm*128 + wm*64 + ((lane >> 4) << 2);
    int cbase = bn*128 + wn*64 + (lane & 15);
    int b1v[4], b2v[4];
    #pragma unroll
    for (int ni = 0; ni < 4; ++ni){
        b1v[ni] = bihq[n*NG + cbase + ni*16];
        b2v[ni] = 32 * bhhq[n*NG + cbase + ni*16];
    }
    // C preload ([n][h][b], word-packed rows) — latency hides under GEMM
    int* Cw = (int*)(C + ((long)(n*HID + hglob))*BATCH + rbase);
    int cold[4];
    #pragma unroll
    for (int mi = 0; mi < 4; ++mi) cold[mi] = Cw[mi*4];

    // W staging geometry (R4): thread covers slab row (tid>>1), 32B half (tid&1)
    int  srow = tid >> 1;
    int  scol = (tid & 1) * 32;
    int  woff = srow*LDAP + scol;
    const signed char* wrow = Wt + ((long)n*NG + bn*128 + srow)*KPAD + scol;

    int am = wm*64 + (lane & 15);
    int bo = wn*64 + (lane & 15);
    int ak = (lane >> 4) * 16;

    // A-fragment direct-global pointers (loop-invariant; slab offsets immediate)
    const signed char* pAh[4];
    #pragma unroll
    for (int mi = 0; mi < 4; ++mi)
        pAh[mi] = Hin + ((long)(n*BATCH + bm*128 + am + mi*16))*HID + ak;

    // prologue: W slab 0 regs + A slab 0 (X) fragments
    int4 rw0 = *(const int4*)wrow;
    int4 rw1 = *(const int4*)(wrow + 16);
    v4i af[2][4];
    #pragma unroll
    for (int mi = 0; mi < 4; ++mi)
        af[0][mi] = *(const v4i*)(xq_t + (bm*128 + am + mi*16)*64 + ak);

    v4i acc2[4][4] = {};
    int q12p[4][4];

    for (int kt = 0; kt < 9; ++kt){
        signed char* Wb = Ws[kt & 1];
        *(int4*)&Wb[woff] = rw0; *(int4*)&Wb[woff + 16] = rw1;
        __syncthreads();
        if (kt < 8){   // prefetch slab kt+1: W regs + A frags (one full phase of cover)
            rw0 = *(const int4*)(wrow + (kt+1)*64);
            rw1 = *(const int4*)(wrow + (kt+1)*64 + 16);
            #pragma unroll
            for (int mi = 0; mi < 4; ++mi)
                af[(kt+1) & 1][mi] = *(const v4i*)(pAh[mi] + kt*64);
        }
        v4i bf[4];
        #pragma unroll
        for (int ni = 0; ni < 4; ++ni) bf[ni] = *(const v4i*)&Wb[(bo + ni*16)*LDAP + ak];
        if (kt == 0){
            v4i acc1[4][4] = {};
            #pragma unroll
            for (int mi = 0; mi < 4; ++mi)
                #pragma unroll
                for (int ni = 0; ni < 4; ++ni)
                    acc1[mi][ni] = __builtin_amdgcn_mfma_i32_16x16x64_i8(af[0][mi], bf[ni], acc1[mi][ni], 0, 0, 0);
            // pack q12 now (frees acc1 registers early)
            #pragma unroll
            for (int mi = 0; mi < 4; ++mi)
                #pragma unroll
                for (int ni = 0; ni < 4; ++ni){
                    int pk = 0;
                    #pragma unroll
                    for (int r = 0; r < 4; ++r){
                        int q = clamp127((int)rintf((float)(acc1[mi][ni][r] + b1v[ni]) * 0.25f));
                        pk |= (q & 255) << (8*r);
                    }
                    q12p[mi][ni] = pk;
                }
        } else {
            #pragma unroll
            for (int mi = 0; mi < 4; ++mi)
                #pragma unroll
                for (int ni = 0; ni < 4; ++ni)
                    acc2[mi][ni] = __builtin_amdgcn_mfma_i32_16x16x64_i8(af[kt & 1][mi], bf[ni], acc2[mi][ni], 0, 0, 0);
        }
    }

    // fused epilogue: gates -> cell update; H bytes out, C word RMW (R4 math)
    #pragma unroll
    for (int mi = 0; mi < 4; ++mi){
        int cw = cold[mi];
        int cnew = 0;
        #pragma unroll
        for (int r = 0; r < 4; ++r){
            int g4[4];
            #pragma unroll
            for (int ni = 0; ni < 4; ++ni){
                int S2  = acc2[mi][ni][r] + b2v[ni];
                int q13 = clamp127((int)rintf((float)S2 * 0.0078125f));
                int q12 = (signed char)(q12p[mi][ni] >> (8*r));
                g4[ni]  = clamp127(q12 + q13);
            }
            int ig = s_sig[g4[0] + 127];
            int jg = s_th [g4[1] + 127];
            int fg = s_sig[g4[2] + 127];
            int og = s_sig[g4[3] + 127];
            int cc = (signed char)(cw >> (8*r));
            int gc = clamp127((int)rintf((float)(cc * fg) * 0.0078125f));   // /128
            int ai = clamp127((int)rintf((float)(ig * jg) * 0.0078125f));   // /128
            int nc = clamp127((int)rintf((float)(4*gc + ai) * 0.25f));      // /4
            int ac = s_th[nc + 127];
            int nh = clamp127((int)rintf((float)(ac * og) * (1.0f/512.0f)));// /512
            cnew |= (nc & 255) << (8*r);
            Hout[((long)(n*BATCH) + rbase + mi*16 + r)*HID + hglob] = (signed char)nh;
        }
        Cw[mi*4] = cnew;
    }
}

// ---------------- final fc ----------------
__global__ __launch_bounds__(256) void k_fc(const signed char* __restrict__ H,
                                            const signed char* __restrict__ fcwt,
                                            const int* __restrict__ fcbq,
                                            float* __restrict__ out){
    int wave = threadIdx.x >> 6, lane = threadIdx.x & 63;
    int nb = blockIdx.x * 4 + wave;                // n*1024+b
    int n = nb >> 10, b = nb & 1023;
    const signed char* h = H + (long)nb * HID + lane * 8;
    int2 hv = *(const int2*)h;
    int acc[3] = {0, 0, 0};
    #pragma unroll
    for (int c = 0; c < 3; ++c){
        const signed char* wp = fcwt + ((long)(n*3 + c))*512 + lane*8;
        int2 wv = *(const int2*)wp;
        int s = 0;
        #pragma unroll
        for (int e = 0; e < 4; ++e){
            s += (int)(signed char)(hv.x >> (8*e)) * (int)(signed char)(wv.x >> (8*e));
            s += (int)(signed char)(hv.y >> (8*e)) * (int)(signed char)(wv.y >> (8*e));
        }
        acc[c] = s;
    }
    #pragma unroll
    for (int off = 32; off; off >>= 1){
        acc[0] += __shfl_down(acc[0], off, 64);
        acc[1] += __shfl_down(acc[1], off, 64);
        acc[2] += __shfl_down(acc[2], off, 64);
    }
    if (lane == 0){
        #pragma unroll
        for (int c = 0; c < 3; ++c){
            int v = acc[c] + 32 * fcbq[n*3 + c];
            int q = clamp127((int)rintf((float)v * (1.0f/512.0f)));
            out[b*12 + n*3 + c] = (float)q * 0.125f;
        }
    }
}

extern "C" void kernel_launch(void* const* d_in, const int* in_sizes, int n_in,
                              void* d_out, int out_size, void* d_ws, size_t ws_size,
                              hipStream_t stream)
{
    const float* x   = (const float*)d_in[0];
    const float* wih = (const float*)d_in[1];
    const float* whh = (const float*)d_in[2];
    const float* bih = (const float*)d_in[3];
    const float* bhh = (const float*)d_in[4];
    const float* fcw = (const float*)d_in[6];
    const float* fcb = (const float*)d_in[7];
    float* out = (float*)d_out;
    (void)in_sizes; (void)n_in; (void)out_size; (void)ws_size;

    char* p = (char*)d_ws;
    auto alloc = [&](size_t nbytes){ char* r = p; p += (nbytes + 255) & ~(size_t)255; return r; };
    signed char* Xq   = (signed char*)alloc((size_t)T_STEPS*BATCH*64);
    signed char* Wt   = (signed char*)alloc((size_t)NBLK*NG*KPAD);
    signed char* Hb0  = (signed char*)alloc((size_t)NBLK*BATCH*HID);
    signed char* Hb1  = (signed char*)alloc((size_t)NBLK*BATCH*HID);
    signed char* Cb   = (signed char*)alloc((size_t)NBLK*BATCH*HID);
    int*         bihq = (int*)alloc((size_t)NBLK*NG*4);
    int*         bhhq = (int*)alloc((size_t)NBLK*NG*4);
    signed char* fcwt = (signed char*)alloc((size_t)NBLK*3*512);
    int*         fcbq = (int*)alloc((size_t)NBLK*3*4);
    signed char* sigl = (signed char*)alloc(256);
    signed char* thl  = (signed char*)alloc(256);

    k_quant_x   <<<(T_STEPS*BATCH*64)/256, 256, 0, stream>>>(x, Xq);
    k_quant_w   <<<(NBLK*NG*KPAD)/256,     256, 0, stream>>>(wih, whh, Wt);
    k_quant_bias<<<(NBLK*NG)/256,          256, 0, stream>>>(bih, bhh, bihq, bhhq);
    k_quant_fc  <<<(NBLK*3*512)/256,       256, 0, stream>>>(fcw, fcb, fcwt, fcbq);
    k_luts      <<<1, 256, 0, stream>>>(sigl, thl);
    hipMemsetAsync(Hb0, 0, (size_t)3*NBLK*BATCH*HID, stream);   // Hb0+Hb1+Cb contiguous

    for (int t = 0; t < T_STEPS; ++t){
        const signed char* Hi = (t & 1) ? Hb1 : Hb0;
        signed char*       Ho = (t & 1) ? Hb0 : Hb1;
        k_step<<<512, 256, 0, stream>>>(Xq + (size_t)t*BATCH*64, Hi, Ho, Cb, Wt, bihq, bhhq, sigl, thl);
    }
    k_fc<<<(NBLK*BATCH)/4, 256, 0, stream>>>(Hb0, fcwt, fcbq, out);   // t=99 wrote Hb0
}

// Round 11
// 1443.722 us; speedup vs baseline: 1.3615x; 1.2720x over previous
//
#include <hip/hip_runtime.h>
#include <math.h>

#define T_STEPS 100
#define BATCH   1024
#define INDIM   40
#define HID     512
#define NBLK    4
#define KPAD    576          // 64 (padded x) + 512 (h)
#define NG      2048         // 4*HID gate width
#define LDAP    80           // padded LDS row stride (bytes) for 64B k-slab

typedef int v4i __attribute__((ext_vector_type(4)));

// Bit-faithful emulation of the reference f32 _pact: sign(x)*0.5*((|x| - ||x|-a|) + a)
__device__ __forceinline__ float pact_f(float x, float a){
    float u = fabsf(x);
    float v = fabsf(u - a);
    float s = (x > 0.f) ? 1.f : ((x < 0.f) ? -1.f : 0.f);
    return (s * 0.5f) * ((u - v) + a);
}
__device__ __forceinline__ int quant_int(float x, float inv_a){
    float xs = x * inv_a;
    xs = fminf(fmaxf(xs, -127.f/128.f), 127.f/128.f);
    return (int)rintf(xs * 128.f);
}
__device__ __forceinline__ int clamp127(int v){
    return v > 127 ? 127 : (v < -127 ? -127 : v);
}

// ---------------- setup kernels ----------------
__global__ __launch_bounds__(256) void k_quant_x(const float* __restrict__ x,
                                                 signed char* __restrict__ xq){
    int idx = blockIdx.x * 256 + threadIdx.x;     // over T*B*64
    int k = idx & 63; int tb = idx >> 6;
    signed char q = 0;
    if (k < INDIM){
        float xv = x[tb * INDIM + k];
        float pv = pact_f(xv, 128.f);
        q = (signed char)quant_int(pv, 1.f/128.f);
    }
    xq[idx] = q;
}

// W stored as Wt[n][c_new][k]; c_new = (h>>4)*64 + gate*16 + (h&15)  <->  o = gate*512 + h
__global__ __launch_bounds__(256) void k_quant_w(const float* __restrict__ wih,
                                                 const float* __restrict__ whh,
                                                 signed char* __restrict__ wt){
    int idx = blockIdx.x * 256 + threadIdx.x;     // over NBLK*NG*KPAD
    int kk = idx % KPAD;
    int no = idx / KPAD;
    int c  = no % NG;
    int n  = no / NG;
    int gate = (c >> 4) & 3;
    int h    = ((c >> 6) << 4) | (c & 15);
    int o    = gate * 512 + h;
    float w;
    if (kk < INDIM)      w = wih[((long)n*INDIM + kk)*NG + o];
    else if (kk < 64)    { wt[idx] = 0; return; }
    else                 w = whh[((long)n*HID + (kk-64))*NG + o];
    w = fminf(fmaxf(w, -1.f), 1.f);
    wt[idx] = (signed char)quant_int(w, 1.f);
}

__global__ __launch_bounds__(256) void k_quant_bias(const float* __restrict__ bih,
                                                    const float* __restrict__ bhh,
                                                    int* __restrict__ bihq,
                                                    int* __restrict__ bhhq){
    int idx = blockIdx.x * 256 + threadIdx.x;     // NBLK*NG, permuted order
    int c = idx % NG; int n = idx / NG;
    int gate = (c >> 4) & 3;
    int h    = ((c >> 6) << 4) | (c & 15);
    int o    = gate * 512 + h;
    bihq[idx] = quant_int(bih[n*NG + o], 1.f);
    bhhq[idx] = quant_int(bhh[n*NG + o], 1.f);
}

__global__ __launch_bounds__(256) void k_quant_fc(const float* __restrict__ fcw,
                                                  const float* __restrict__ fcb,
                                                  signed char* __restrict__ fcwt,
                                                  int* __restrict__ fcbq){
    int idx = blockIdx.x * 256 + threadIdx.x;     // NBLK*3*512
    if (idx < NBLK*3*512){
        int k = idx % 512; int nc = idx / 512; int c = nc % 3; int n = nc / 3;
        float w = fcw[((long)n*HID + k)*3 + c];
        w = fminf(fmaxf(w, -1.f), 1.f);
        fcwt[idx] = (signed char)quant_int(w, 1.f);
    }
    if (idx < NBLK*3) fcbq[idx] = quant_int(fcb[idx], 1.f);
}

__global__ void k_luts(signed char* __restrict__ sigl, signed char* __restrict__ thl){
    int i = threadIdx.x;
    if (i < 255){
        double xv = (double)(i - 127) / 32.0;
        float s = (float)(1.0 / (1.0 + exp(-xv)));
        float t = (float)tanh(xv);
        sigl[i] = (signed char)quant_int(pact_f(s, 1.f), 1.f);
        thl[i]  = (signed char)quant_int(pact_f(t, 1.f), 1.f);
    }
}

// ---------------- fused per-step kernel: gates GEMM + cell update ----------------
// 512 blocks, 512 threads = 8 waves (4wm x 2wn), block tile 128x128,
// wave tile 32x64. Same staging rhythm as R4 (reg double-buffer through LDS,
// LDAP=80 pad, ONE __syncthreads per kt) but DOUBLE the occupancy:
// 16 waves/CU (launch_bounds(512,4)) to hide barrier/VMEM/LUT latency.
// XCD-affine: bid&7 = XCD; two XCDs serve one n (W+H L2-resident).
__global__ __launch_bounds__(512, 4) void k_step(const signed char* __restrict__ xq_t,
                                                 const signed char* __restrict__ Hin,
                                                 signed char* __restrict__ Hout,
                                                 signed char* __restrict__ C,
                                                 const signed char* __restrict__ Wt,
                                                 const int* __restrict__ bihq,
                                                 const int* __restrict__ bhhq,
                                                 const signed char* __restrict__ sigl,
                                                 const signed char* __restrict__ thl){
    __shared__ __align__(16) signed char As[2][128*LDAP];
    __shared__ __align__(16) signed char Ws[2][128*LDAP];
    __shared__ signed char s_sig[256], s_th[256];

    int bid = blockIdx.x;
    int xcd = bid & 7, slot = bid >> 3;            // slot in [0,64)
    int n   = xcd >> 1;
    int idx = ((xcd & 1) << 6) | slot;             // [0,128)
    int bm  = idx & 7;                             // 8 x 128-row blocks
    int bn  = idx >> 3;                            // 16 x 128-col blocks

    int tid  = threadIdx.x;
    int lane = tid & 63;
    int wave = tid >> 6;                           // 0..7
    int wm = wave >> 1, wn = wave & 1;             // 4 x 2

    if (tid < 255){ s_sig[tid] = sigl[tid]; s_th[tid] = thl[tid]; }

    // per-lane output coordinates (wave tile 32 rows x 64 cols)
    int hglob = bn*32 + wn*16 + (lane & 15);
    int rbase = bm*128 + wm*32 + ((lane >> 4) << 2);
    int cbase = bn*128 + wn*64 + (lane & 15);
    int b1v[4], b2v[4];
    #pragma unroll
    for (int ni = 0; ni < 4; ++ni){
        b1v[ni] = bihq[n*NG + cbase + ni*16];
        b2v[ni] = 32 * bhhq[n*NG + cbase + ni*16];
    }
    // C preload ([n][h][b], word-packed rows) — latency hides under GEMM
    int* Cw = (int*)(C + ((long)(n*HID + hglob))*BATCH + rbase);
    int cold[2];
    #pragma unroll
    for (int mi = 0; mi < 2; ++mi) cold[mi] = Cw[mi*4];

    // staging geometry: thread covers slab row (tid>>2), 16B chunk (tid&3)
    int  srow = tid >> 2;
    int  scol = (tid & 3) * 16;
    int  aoff = srow*LDAP + scol;
    const signed char* hrow = Hin + ((long)(n*BATCH + bm*128 + srow))*HID + scol;
    const signed char* wrow = Wt  + ((long)n*NG + bn*128 + srow)*KPAD + scol;

    int am = wm*32 + (lane & 15);
    int bo = wn*64 + (lane & 15);
    int ak = (lane >> 4) * 16;

    // prologue: slab 0 (X part + W k=0..63)
    const signed char* xrow = xq_t + (bm*128 + srow)*64 + scol;
    int4 ra0 = *(const int4*)xrow;
    int4 rw0 = *(const int4*)wrow;

    v4i acc1[2][4] = {};
    v4i acc2[2][4] = {};
    int q12p[2][4];

    for (int kt = 0; kt < 9; ++kt){
        signed char* Ab = As[kt & 1];
        signed char* Wb = Ws[kt & 1];
        *(int4*)&Ab[aoff] = ra0;
        *(int4*)&Wb[aoff] = rw0;
        __syncthreads();
        if (kt < 8){   // issue next slab loads; latency covered by frags+MFMA(+next sync)
            ra0 = *(const int4*)(hrow + kt*64);
            rw0 = *(const int4*)(wrow + (kt+1)*64);
        }
        v4i af[2], bf[4];
        #pragma unroll
        for (int mi = 0; mi < 2; ++mi) af[mi] = *(const v4i*)&Ab[(am + mi*16)*LDAP + ak];
        #pragma unroll
        for (int ni = 0; ni < 4; ++ni) bf[ni] = *(const v4i*)&Wb[(bo + ni*16)*LDAP + ak];
        if (kt == 0){
            #pragma unroll
            for (int mi = 0; mi < 2; ++mi)
                #pragma unroll
                for (int ni = 0; ni < 4; ++ni)
                    acc1[mi][ni] = __builtin_amdgcn_mfma_i32_16x16x64_i8(af[mi], bf[ni], acc1[mi][ni], 0, 0, 0);
            // pack q12 now (frees acc1 registers early)
            #pragma unroll
            for (int mi = 0; mi < 2; ++mi)
                #pragma unroll
                for (int ni = 0; ni < 4; ++ni){
                    int pk = 0;
                    #pragma unroll
                    for (int r = 0; r < 4; ++r){
                        int q = clamp127((int)rintf((float)(acc1[mi][ni][r] + b1v[ni]) * 0.25f));
                        pk |= (q & 255) << (8*r);
                    }
                    q12p[mi][ni] = pk;
                }
        } else {
            #pragma unroll
            for (int mi = 0; mi < 2; ++mi)
                #pragma unroll
                for (int ni = 0; ni < 4; ++ni)
                    acc2[mi][ni] = __builtin_amdgcn_mfma_i32_16x16x64_i8(af[mi], bf[ni], acc2[mi][ni], 0, 0, 0);
        }
    }

    // fused epilogue: gates -> cell update; H bytes out, C word RMW (R4 math)
    #pragma unroll
    for (int mi = 0; mi < 2; ++mi){
        int cw = cold[mi];
        int cnew = 0;
        #pragma unroll
        for (int r = 0; r < 4; ++r){
            int g4[4];
            #pragma unroll
            for (int ni = 0; ni < 4; ++ni){
                int S2  = acc2[mi][ni][r] + b2v[ni];
                int q13 = clamp127((int)rintf((float)S2 * 0.0078125f));
                int q12 = (signed char)(q12p[mi][ni] >> (8*r));
                g4[ni]  = clamp127(q12 + q13);
            }
            int ig = s_sig[g4[0] + 127];
            int jg = s_th [g4[1] + 127];
            int fg = s_sig[g4[2] + 127];
            int og = s_sig[g4[3] + 127];
            int cc = (signed char)(cw >> (8*r));
            int gc = clamp127((int)rintf((float)(cc * fg) * 0.0078125f));   // /128
            int ai = clamp127((int)rintf((float)(ig * jg) * 0.0078125f));   // /128
            int nc = clamp127((int)rintf((float)(4*gc + ai) * 0.25f));      // /4
            int ac = s_th[nc + 127];
            int nh = clamp127((int)rintf((float)(ac * og) * (1.0f/512.0f)));// /512
            cnew |= (nc & 255) << (8*r);
            Hout[((long)(n*BATCH) + rbase + mi*16 + r)*HID + hglob] = (signed char)nh;
        }
        Cw[mi*4] = cnew;
    }
}

// ---------------- final fc ----------------
__global__ __launch_bounds__(256) void k_fc(const signed char* __restrict__ H,
                                            const signed char* __restrict__ fcwt,
                                            const int* __restrict__ fcbq,
                                            float* __restrict__ out){
    int wave = threadIdx.x >> 6, lane = threadIdx.x & 63;
    int nb = blockIdx.x * 4 + wave;                // n*1024+b
    int n = nb >> 10, b = nb & 1023;
    const signed char* h = H + (long)nb * HID + lane * 8;
    int2 hv = *(const int2*)h;
    int acc[3] = {0, 0, 0};
    #pragma unroll
    for (int c = 0; c < 3; ++c){
        const signed char* wp = fcwt + ((long)(n*3 + c))*512 + lane*8;
        int2 wv = *(const int2*)wp;
        int s = 0;
        #pragma unroll
        for (int e = 0; e < 4; ++e){
            s += (int)(signed char)(hv.x >> (8*e)) * (int)(signed char)(wv.x >> (8*e));
            s += (int)(signed char)(hv.y >> (8*e)) * (int)(signed char)(wv.y >> (8*e));
        }
        acc[c] = s;
    }
    #pragma unroll
    for (int off = 32; off; off >>= 1){
        acc[0] += __shfl_down(acc[0], off, 64);
        acc[1] += __shfl_down(acc[1], off, 64);
        acc[2] += __shfl_down(acc[2], off, 64);
    }
    if (lane == 0){
        #pragma unroll
        for (int c = 0; c < 3; ++c){
            int v = acc[c] + 32 * fcbq[n*3 + c];
            int q = clamp127((int)rintf((float)v * (1.0f/512.0f)));
            out[b*12 + n*3 + c] = (float)q * 0.125f;
        }
    }
}

extern "C" void kernel_launch(void* const* d_in, const int* in_sizes, int n_in,
                              void* d_out, int out_size, void* d_ws, size_t ws_size,
                              hipStream_t stream)
{
    const float* x   = (const float*)d_in[0];
    const float* wih = (const float*)d_in[1];
    const float* whh = (const float*)d_in[2];
    const float* bih = (const float*)d_in[3];
    const float* bhh = (const float*)d_in[4];
    const float* fcw = (const float*)d_in[6];
    const float* fcb = (const float*)d_in[7];
    float* out = (float*)d_out;
    (void)in_sizes; (void)n_in; (void)out_size; (void)ws_size;

    char* p = (char*)d_ws;
    auto alloc = [&](size_t nbytes){ char* r = p; p += (nbytes + 255) & ~(size_t)255; return r; };
    signed char* Xq   = (signed char*)alloc((size_t)T_STEPS*BATCH*64);
    signed char* Wt   = (signed char*)alloc((size_t)NBLK*NG*KPAD);
    signed char* Hb0  = (signed char*)alloc((size_t)NBLK*BATCH*HID);
    signed char* Hb1  = (signed char*)alloc((size_t)NBLK*BATCH*HID);
    signed char* Cb   = (signed char*)alloc((size_t)NBLK*BATCH*HID);
    int*         bihq = (int*)alloc((size_t)NBLK*NG*4);
    int*         bhhq = (int*)alloc((size_t)NBLK*NG*4);
    signed char* fcwt = (signed char*)alloc((size_t)NBLK*3*512);
    int*         fcbq = (int*)alloc((size_t)NBLK*3*4);
    signed char* sigl = (signed char*)alloc(256);
    signed char* thl  = (signed char*)alloc(256);

    k_quant_x   <<<(T_STEPS*BATCH*64)/256, 256, 0, stream>>>(x, Xq);
    k_quant_w   <<<(NBLK*NG*KPAD)/256,     256, 0, stream>>>(wih, whh, Wt);
    k_quant_bias<<<(NBLK*NG)/256,          256, 0, stream>>>(bih, bhh, bihq, bhhq);
    k_quant_fc  <<<(NBLK*3*512)/256,       256, 0, stream>>>(fcw, fcb, fcwt, fcbq);
    k_luts      <<<1, 256, 0, stream>>>(sigl, thl);
    hipMemsetAsync(Hb0, 0, (size_t)3*NBLK*BATCH*HID, stream);   // Hb0+Hb1+Cb contiguous

    for (int t = 0; t < T_STEPS; ++t){
        const signed char* Hi = (t & 1) ? Hb1 : Hb0;
        signed char*       Ho = (t & 1) ? Hb0 : Hb1;
        k_step<<<512, 512, 0, stream>>>(Xq + (size_t)t*BATCH*64, Hi, Ho, Cb, Wt, bihq, bhhq, sigl, thl);
    }
    k_fc<<<(NBLK*BATCH)/4, 256, 0, stream>>>(Hb0, fcwt, fcbq, out);   // t=99 wrote Hb0
}

// Round 12
// 1260.627 us; speedup vs baseline: 1.5593x; 1.1452x over previous
//
#include <hip/hip_runtime.h>
#include <math.h>

#define T_STEPS 100
#define BATCH   1024
#define INDIM   40
#define HID     512
#define NBLK    4
#define KPAD    576          // 64 (padded x) + 512 (h)
#define NG      2048         // 4*HID gate width
#define LDAP    80           // padded LDS row stride (bytes) for 64B k-slab

typedef int v4i __attribute__((ext_vector_type(4)));

// Bit-faithful emulation of the reference f32 _pact: sign(x)*0.5*((|x| - ||x|-a|) + a)
__device__ __forceinline__ float pact_f(float x, float a){
    float u = fabsf(x);
    float v = fabsf(u - a);
    float s = (x > 0.f) ? 1.f : ((x < 0.f) ? -1.f : 0.f);
    return (s * 0.5f) * ((u - v) + a);
}
__device__ __forceinline__ int quant_int(float x, float inv_a){
    float xs = x * inv_a;
    xs = fminf(fmaxf(xs, -127.f/128.f), 127.f/128.f);
    return (int)rintf(xs * 128.f);
}
__device__ __forceinline__ int clamp127(int v){
    return v > 127 ? 127 : (v < -127 ? -127 : v);
}

// ---------------- merged setup kernel (grid-strided; one dispatch) ----------------
// Region 0: Xq  (T*B*64 = 6,553,600 elems)
// Region 1: Wt  (NBLK*NG*KPAD = 4,718,592)
// Region 2: biases (NBLK*NG = 8192)
// Region 3: fc weights (NBLK*3*512 = 6144) + fc biases (NBLK*3 = 12)
// Region 4: LUTs (255)
#define SETUP_N0 (T_STEPS*BATCH*64)
#define SETUP_N1 (NBLK*NG*KPAD)
#define SETUP_N2 (NBLK*NG)
#define SETUP_N3 (NBLK*3*512)
#define SETUP_TOTAL (SETUP_N0 + SETUP_N1 + SETUP_N2 + SETUP_N3 + NBLK*3 + 255)

__global__ __launch_bounds__(256) void k_setup(const float* __restrict__ x,
                                               const float* __restrict__ wih,
                                               const float* __restrict__ whh,
                                               const float* __restrict__ bih,
                                               const float* __restrict__ bhh,
                                               const float* __restrict__ fcw,
                                               const float* __restrict__ fcb,
                                               signed char* __restrict__ xq,
                                               signed char* __restrict__ wt,
                                               int* __restrict__ bihq,
                                               int* __restrict__ bhhq,
                                               signed char* __restrict__ fcwt,
                                               int* __restrict__ fcbq,
                                               signed char* __restrict__ sigl,
                                               signed char* __restrict__ thl){
    for (long idx = blockIdx.x * 256 + threadIdx.x; idx < SETUP_TOTAL; idx += (long)gridDim.x * 256){
        long r = idx;
        if (r < SETUP_N0){
            // ---- quantize X (pad 40 -> 64) ----
            int k = (int)(r & 63); long tb = r >> 6;
            signed char q = 0;
            if (k < INDIM){
                float xv = x[tb * INDIM + k];
                q = (signed char)quant_int(pact_f(xv, 128.f), 1.f/128.f);
            }
            xq[r] = q;
            continue;
        }
        r -= SETUP_N0;
        if (r < SETUP_N1){
            // ---- quantize + permute W: Wt[n][c_new][k] ----
            int kk = (int)(r % KPAD);
            int no = (int)(r / KPAD);
            int c  = no % NG;
            int n  = no / NG;
            int gate = (c >> 4) & 3;
            int h    = ((c >> 6) << 4) | (c & 15);
            int o    = gate * 512 + h;
            float w;
            if (kk < INDIM)      w = wih[((long)n*INDIM + kk)*NG + o];
            else if (kk < 64)    { wt[r] = 0; continue; }
            else                 w = whh[((long)n*HID + (kk-64))*NG + o];
            w = fminf(fmaxf(w, -1.f), 1.f);
            wt[r] = (signed char)quant_int(w, 1.f);
            continue;
        }
        r -= SETUP_N1;
        if (r < SETUP_N2){
            // ---- quantize biases (permuted order) ----
            int c = (int)(r % NG); int n = (int)(r / NG);
            int gate = (c >> 4) & 3;
            int h    = ((c >> 6) << 4) | (c & 15);
            int o    = gate * 512 + h;
            bihq[r] = quant_int(bih[n*NG + o], 1.f);
            bhhq[r] = quant_int(bhh[n*NG + o], 1.f);
            continue;
        }
        r -= SETUP_N2;
        if (r < SETUP_N3){
            // ---- quantize fc weights (transposed [n][c][k]) ----
            int k = (int)(r % 512); int nc = (int)(r / 512); int c = nc % 3; int n = nc / 3;
            float w = fcw[((long)n*HID + k)*3 + c];
            w = fminf(fmaxf(w, -1.f), 1.f);
            fcwt[r] = (signed char)quant_int(w, 1.f);
            continue;
        }
        r -= SETUP_N3;
        if (r < NBLK*3){
            fcbq[r] = quant_int(fcb[r], 1.f);
            continue;
        }
        r -= NBLK*3;
        {
            // ---- sigmoid/tanh LUTs over the 255 possible gate levels ----
            double xv = (double)((int)r - 127) / 32.0;
            float s = (float)(1.0 / (1.0 + exp(-xv)));
            float t = (float)tanh(xv);
            sigl[r] = (signed char)quant_int(pact_f(s, 1.f), 1.f);
            thl[r]  = (signed char)quant_int(pact_f(t, 1.f), 1.f);
        }
    }
}

// ---------------- fused per-step kernel: gates GEMM + cell update (R4) ----------------
// 512 blocks (2/CU), 4 waves (2m x 2n), block tile 128x128, wave tile 64x64.
// Double-buffered A and W k-slabs, ONE __syncthreads per kt.
// XCD-affine: bid&7 = XCD; two XCDs serve one n (W+H L2-resident).
__global__ __launch_bounds__(256, 2) void k_step(const signed char* __restrict__ xq_t,
                                                 const signed char* __restrict__ Hin,
                                                 signed char* __restrict__ Hout,
                                                 signed char* __restrict__ C,
                                                 const signed char* __restrict__ Wt,
                                                 const int* __restrict__ bihq,
                                                 const int* __restrict__ bhhq,
                                                 const signed char* __restrict__ sigl,
                                                 const signed char* __restrict__ thl){
    __shared__ __align__(16) signed char As[2][128*LDAP];
    __shared__ __align__(16) signed char Ws[2][128*LDAP];
    __shared__ signed char s_sig[256], s_th[256];

    int bid = blockIdx.x;
    int xcd = bid & 7, slot = bid >> 3;            // slot in [0,64)
    int n   = xcd >> 1;
    int idx = ((xcd & 1) << 6) | slot;             // [0,128)
    int bm  = idx & 7;                             // 8 x 128-row blocks
    int bn  = idx >> 3;                            // 16 x 128-col blocks

    int tid  = threadIdx.x;
    int lane = tid & 63;
    int wave = tid >> 6;
    int wm = wave >> 1, wn = wave & 1;

    if (tid < 255){ s_sig[tid] = sigl[tid]; s_th[tid] = thl[tid]; }

    // per-lane output coordinates
    int hglob = bn*32 + wn*16 + (lane & 15);
    int rbase = bm*128 + wm*64 + ((lane >> 4) << 2);
    int cbase = bn*128 + wn*64 + (lane & 15);
    int b1v[4], b2v[4];
    #pragma unroll
    for (int ni = 0; ni < 4; ++ni){
        b1v[ni] = bihq[n*NG + cbase + ni*16];
        b2v[ni] = 32 * bhhq[n*NG + cbase + ni*16];
    }
    // C preload ([n][h][b], word-packed rows) — latency hides under GEMM
    int* Cw = (int*)(C + ((long)(n*HID + hglob))*BATCH + rbase);
    int cold[4];
    #pragma unroll
    for (int mi = 0; mi < 4; ++mi) cold[mi] = Cw[mi*4];

    // staging geometry: thread covers slab row (tid>>1), 32B half (tid&1)
    int  srow = tid >> 1;
    int  scol = (tid & 1) * 32;
    int  aoff = srow*LDAP + scol;
    const signed char* hrow = Hin + ((long)(n*BATCH + bm*128 + srow))*HID + scol;
    const signed char* wrow = Wt  + ((long)n*NG + bn*128 + srow)*KPAD + scol;

    int am = wm*64 + (lane & 15);
    int bo = wn*64 + (lane & 15);
    int ak = (lane >> 4) * 16;

    // prologue: slab 0 (X part + W k=0..63)
    const signed char* xrow = xq_t + (bm*128 + srow)*64 + scol;
    int4 ra0 = *(const int4*)xrow;
    int4 ra1 = *(const int4*)(xrow + 16);
    int4 rw0 = *(const int4*)wrow;
    int4 rw1 = *(const int4*)(wrow + 16);

    v4i acc1[4][4] = {};
    v4i acc2[4][4] = {};
    int q12p[4][4];

    for (int kt = 0; kt < 9; ++kt){
        signed char* Ab = As[kt & 1];
        signed char* Wb = Ws[kt & 1];
        *(int4*)&Ab[aoff] = ra0; *(int4*)&Ab[aoff + 16] = ra1;
        *(int4*)&Wb[aoff] = rw0; *(int4*)&Wb[aoff + 16] = rw1;
        __syncthreads();
        if (kt < 8){   // issue next slab loads; latency covered by frags+MFMA(+next sync)
            ra0 = *(const int4*)(hrow + kt*64);
            ra1 = *(const int4*)(hrow + kt*64 + 16);
            rw0 = *(const int4*)(wrow + (kt+1)*64);
            rw1 = *(const int4*)(wrow + (kt+1)*64 + 16);
        }
        v4i af[4], bf[4];
        #pragma unroll
        for (int mi = 0; mi < 4; ++mi) af[mi] = *(const v4i*)&Ab[(am + mi*16)*LDAP + ak];
        #pragma unroll
        for (int ni = 0; ni < 4; ++ni) bf[ni] = *(const v4i*)&Wb[(bo + ni*16)*LDAP + ak];
        if (kt == 0){
            #pragma unroll
            for (int mi = 0; mi < 4; ++mi)
                #pragma unroll
                for (int ni = 0; ni < 4; ++ni)
                    acc1[mi][ni] = __builtin_amdgcn_mfma_i32_16x16x64_i8(af[mi], bf[ni], acc1[mi][ni], 0, 0, 0);
            // pack q12 now (frees acc1 registers early)
            #pragma unroll
            for (int mi = 0; mi < 4; ++mi)
                #pragma unroll
                for (int ni = 0; ni < 4; ++ni){
                    int pk = 0;
                    #pragma unroll
                    for (int r = 0; r < 4; ++r){
                        int q = clamp127((int)rintf((float)(acc1[mi][ni][r] + b1v[ni]) * 0.25f));
                        pk |= (q & 255) << (8*r);
                    }
                    q12p[mi][ni] = pk;
                }
        } else {
            #pragma unroll
            for (int mi = 0; mi < 4; ++mi)
                #pragma unroll
                for (int ni = 0; ni < 4; ++ni)
                    acc2[mi][ni] = __builtin_amdgcn_mfma_i32_16x16x64_i8(af[mi], bf[ni], acc2[mi][ni], 0, 0, 0);
        }
    }

    // fused epilogue: gates -> cell update; H bytes out, C word RMW
    #pragma unroll
    for (int mi = 0; mi < 4; ++mi){
        int cw = cold[mi];
        int cnew = 0;
        #pragma unroll
        for (int r = 0; r < 4; ++r){
            int g4[4];
            #pragma unroll
            for (int ni = 0; ni < 4; ++ni){
                int S2  = acc2[mi][ni][r] + b2v[ni];
                int q13 = clamp127((int)rintf((float)S2 * 0.0078125f));
                int q12 = (signed char)(q12p[mi][ni] >> (8*r));
                g4[ni]  = clamp127(q12 + q13);
            }
            int ig = s_sig[g4[0] + 127];
            int jg = s_th [g4[1] + 127];
            int fg = s_sig[g4[2] + 127];
            int og = s_sig[g4[3] + 127];
            int cc = (signed char)(cw >> (8*r));
            int gc = clamp127((int)rintf((float)(cc * fg) * 0.0078125f));   // /128
            int ai = clamp127((int)rintf((float)(ig * jg) * 0.0078125f));   // /128
            int nc = clamp127((int)rintf((float)(4*gc + ai) * 0.25f));      // /4
            int ac = s_th[nc + 127];
            int nh = clamp127((int)rintf((float)(ac * og) * (1.0f/512.0f)));// /512
            cnew |= (nc & 255) << (8*r);
            Hout[((long)(n*BATCH) + rbase + mi*16 + r)*HID + hglob] = (signed char)nh;
        }
        Cw[mi*4] = cnew;
    }
}

// ---------------- final fc ----------------
__global__ __launch_bounds__(256) void k_fc(const signed char* __restrict__ H,
                                            const signed char* __restrict__ fcwt,
                                            const int* __restrict__ fcbq,
                                            float* __restrict__ out){
    int wave = threadIdx.x >> 6, lane = threadIdx.x & 63;
    int nb = blockIdx.x * 4 + wave;                // n*1024+b
    int n = nb >> 10, b = nb & 1023;
    const signed char* h = H + (long)nb * HID + lane * 8;
    int2 hv = *(const int2*)h;
    int acc[3] = {0, 0, 0};
    #pragma unroll
    for (int c = 0; c < 3; ++c){
        const signed char* wp = fcwt + ((long)(n*3 + c))*512 + lane*8;
        int2 wv = *(const int2*)wp;
        int s = 0;
        #pragma unroll
        for (int e = 0; e < 4; ++e){
            s += (int)(signed char)(hv.x >> (8*e)) * (int)(signed char)(wv.x >> (8*e));
            s += (int)(signed char)(hv.y >> (8*e)) * (int)(signed char)(wv.y >> (8*e));
        }
        acc[c] = s;
    }
    #pragma unroll
    for (int off = 32; off; off >>= 1){
        acc[0] += __shfl_down(acc[0], off, 64);
        acc[1] += __shfl_down(acc[1], off, 64);
        acc[2] += __shfl_down(acc[2], off, 64);
    }
    if (lane == 0){
        #pragma unroll
        for (int c = 0; c < 3; ++c){
            int v = acc[c] + 32 * fcbq[n*3 + c];
            int q = clamp127((int)rintf((float)v * (1.0f/512.0f)));
            out[b*12 + n*3 + c] = (float)q * 0.125f;
        }
    }
}

extern "C" void kernel_launch(void* const* d_in, const int* in_sizes, int n_in,
                              void* d_out, int out_size, void* d_ws, size_t ws_size,
                              hipStream_t stream)
{
    const float* x   = (const float*)d_in[0];
    const float* wih = (const float*)d_in[1];
    const float* whh = (const float*)d_in[2];
    const float* bih = (const float*)d_in[3];
    const float* bhh = (const float*)d_in[4];
    const float* fcw = (const float*)d_in[6];
    const float* fcb = (const float*)d_in[7];
    float* out = (float*)d_out;
    (void)in_sizes; (void)n_in; (void)out_size; (void)ws_size;

    char* p = (char*)d_ws;
    auto alloc = [&](size_t nbytes){ char* r = p; p += (nbytes + 255) & ~(size_t)255; return r; };
    signed char* Xq   = (signed char*)alloc((size_t)T_STEPS*BATCH*64);
    signed char* Wt   = (signed char*)alloc((size_t)NBLK*NG*KPAD);
    signed char* Hb0  = (signed char*)alloc((size_t)NBLK*BATCH*HID);
    signed char* Hb1  = (signed char*)alloc((size_t)NBLK*BATCH*HID);
    signed char* Cb   = (signed char*)alloc((size_t)NBLK*BATCH*HID);
    int*         bihq = (int*)alloc((size_t)NBLK*NG*4);
    int*         bhhq = (int*)alloc((size_t)NBLK*NG*4);
    signed char* fcwt = (signed char*)alloc((size_t)NBLK*3*512);
    int*         fcbq = (int*)alloc((size_t)NBLK*3*4);
    signed char* sigl = (signed char*)alloc(256);
    signed char* thl  = (signed char*)alloc(256);

    k_setup<<<2048, 256, 0, stream>>>(x, wih, whh, bih, bhh, fcw, fcb,
                                      Xq, Wt, bihq, bhhq, fcwt, fcbq, sigl, thl);
    hipMemsetAsync(Hb0, 0, (size_t)3*NBLK*BATCH*HID, stream);   // Hb0+Hb1+Cb contiguous

    for (int t = 0; t < T_STEPS; ++t){
        const signed char* Hi = (t & 1) ? Hb1 : Hb0;
        signed char*       Ho = (t & 1) ? Hb0 : Hb1;
        k_step<<<512, 256, 0, stream>>>(Xq + (size_t)t*BATCH*64, Hi, Ho, Cb, Wt, bihq, bhhq, sigl, thl);
    }
    k_fc<<<(NBLK*BATCH)/4, 256, 0, stream>>>(Hb0, fcwt, fcbq, out);   // t=99 wrote Hb0
}